// Round 1
// baseline (1133.514 us; speedup 1.0000x reference)
//
#include <hip/hip_runtime.h>
#include <math.h>

#define PAD_ID 50257
#define B_ 8
#define S_ 2048
#define D_ 2048
#define H_ 16
#define HD_ 128
#define L_ 2
#define DC_ 4096
#define I_ 16384
#define EPS_ 1e-5f

__device__ __forceinline__ int rfl(int x){ return __builtin_amdgcn_readfirstlane(x); }

// ---------------- kA: last non-pad index per sequence ----------------
__global__ __launch_bounds__(256) void kA(const int* __restrict__ ids, int* __restrict__ idx){
  int b = blockIdx.x, t = threadIdx.x;
  __shared__ int red[256];
  int best = -1;
  for (int s = t; s < S_; s += 256)
    if (ids[b*S_+s] != PAD_ID) best = s;   // monotone loop -> best = max nonpad s in this thread's strided set
  red[t] = best; __syncthreads();
  for (int off=128; off; off>>=1){ if (t<off) red[t] = max(red[t], red[t+off]); __syncthreads(); }
  if (t==0) idx[b] = max(red[0], 0);
}

// ---------------- kA2: LN of last-token row -> lnlT[l][d][b] ----------------
__global__ __launch_bounds__(256) void kA2(const float* __restrict__ hs0, const float* __restrict__ hs1,
                    const int* __restrict__ idx,
                    const float* __restrict__ g, const float* __restrict__ bt,
                    float* __restrict__ lnlT){
  int b = blockIdx.x, l = blockIdx.y, t = threadIdx.x;
  const float* hs = (l==0?hs0:hs1);
  const float* row = hs + ((size_t)b*S_ + idx[b])*D_;
  int d0 = t*8;
  float x[8]; float s=0.f, ss=0.f;
  #pragma unroll
  for(int k=0;k<8;k++){ x[k]=row[d0+k]; s+=x[k]; ss+=x[k]*x[k]; }
  __shared__ float r1[256], r2[256];
  r1[t]=s; r2[t]=ss; __syncthreads();
  for(int off=128; off; off>>=1){ if(t<off){ r1[t]+=r1[t+off]; r2[t]+=r2[t+off]; } __syncthreads(); }
  float m = r1[0]*(1.0f/D_); float var = r2[0]*(1.0f/D_) - m*m;
  float rstd = rsqrtf(var + EPS_);
  #pragma unroll
  for(int k=0;k<8;k++){
    int d = d0+k;
    lnlT[((size_t)l*D_ + d)*8 + b] = (x[k]-m)*rstd*g[l*D_+d] + bt[l*D_+d];
  }
}

// ---------------- gemv8: outT[i][b] += sum_c Xt[c][b] * W[c][i] (8 rows) ----------------
__global__ __launch_bounds__(256) void gemv8(
    const float* __restrict__ W, const float* __restrict__ Xt, float* __restrict__ outAcc,
    int C, int N, int cs, long wStride, long xStride, long oStride){
  int t = threadIdx.x;
  int l = blockIdx.z;
  W += (size_t)l*wStride; Xt += (size_t)l*xStride; outAcc += (size_t)l*oStride;
  int lane = t & 63;
  int w = rfl(t >> 6);
  int cpw = C/(cs*4);
  int c0 = (blockIdx.y*4 + w)*cpw;
  float acc[8] = {0,0,0,0,0,0,0,0};
  const float* xp = Xt + (size_t)c0*8;
  const float* wp = W + (size_t)c0*N + (size_t)blockIdx.x*64 + lane;
  #pragma unroll 4
  for (int c=0; c<cpw; c++){
    float wv = wp[(size_t)c*N];
    #pragma unroll
    for(int r=0;r<8;r++) acc[r] += xp[c*8+r]*wv;
  }
  __shared__ float red[4][64][8];
  #pragma unroll
  for(int r=0;r<8;r++) red[w][lane][r] = acc[r];
  __syncthreads();
  if (t < 64){
    #pragma unroll
    for(int r=0;r<8;r++){
      float s = red[0][t][r]+red[1][t][r]+red[2][t][r]+red[3][t][r];
      atomicAdd(&outAcc[((size_t)blockIdx.x*64 + t)*8 + r], s);
    }
  }
}

// ---------------- kC: qk -> gqk[l][b][h][d'], Sg, Sb ----------------
__global__ __launch_bounds__(256) void kC(
    const float* __restrict__ Wk, const float* __restrict__ qT,
    const float* __restrict__ g, const float* __restrict__ bt,
    float* __restrict__ gqk, float* __restrict__ Sg, float* __restrict__ Sb){
  int t = threadIdx.x;
  int dq = blockIdx.x; int h = blockIdx.y; int l = blockIdx.z;
  const float* wkB = Wk + (size_t)l*D_*D_ + h*HD_;
  const float* qB  = qT + ((size_t)l*D_ + h*HD_)*8;
  float sgl[8]={0,0,0,0,0,0,0,0}, sbl[8]={0,0,0,0,0,0,0,0};
  for (int rr=0; rr<2; rr++){
    int dp = dq*512 + rr*256 + t;
    const float* wr = wkB + (size_t)dp*D_;
    float a[8]={0,0,0,0,0,0,0,0};
    #pragma unroll 4
    for (int j=0;j<HD_;j++){
      float wv = wr[j];
      #pragma unroll
      for(int r=0;r<8;r++) a[r] += wv*qB[j*8+r];
    }
    float gg = g[l*D_+dp], bb = bt[l*D_+dp];
    #pragma unroll
    for(int r=0;r<8;r++){
      float gq = gg*a[r];
      gqk[((size_t)(l*8+r)*H_ + h)*D_ + dp] = gq;
      sgl[r] += gq;
      sbl[r] += bb*a[r];
    }
  }
  __shared__ float red[256][8];
  #pragma unroll
  for(int r=0;r<8;r++) red[t][r]=sgl[r];
  __syncthreads();
  for(int off=128; off; off>>=1){ if(t<off){ for(int r=0;r<8;r++) red[t][r]+=red[t+off][r]; } __syncthreads(); }
  if (t<8) atomicAdd(&Sg[(l*8+t)*H_ + h], red[0][t]);
  __syncthreads();
  #pragma unroll
  for(int r=0;r<8;r++) red[t][r]=sbl[r];
  __syncthreads();
  for(int off=128; off; off>>=1){ if(t<off){ for(int r=0;r<8;r++) red[t][r]+=red[t+off][r]; } __syncthreads(); }
  if (t<8) atomicAdd(&Sb[(l*8+t)*H_ + h], red[0][t]);
}

// ---------------- kD: scores pass (reads hs once, LN fused) ----------------
__global__ __launch_bounds__(256) void kD(
    const float* __restrict__ hs0, const float* __restrict__ hs1,
    const float* __restrict__ gqk, const float* __restrict__ Sg, const float* __restrict__ Sb,
    float* __restrict__ scores, float* __restrict__ mu, float* __restrict__ rs){
  int t = threadIdx.x;
  int sc = blockIdx.x, b = blockIdx.y, l = blockIdx.z;
  const float* hs = (l==0?hs0:hs1) + (size_t)b*S_*D_;
  int r = t & 63;
  int jq = rfl(t >> 6);
  int s0 = sc*64;
  __shared__ float lds[64*65];
  float acc[16];
  #pragma unroll
  for(int h=0;h<16;h++) acc[h]=0.f;
  float sum=0.f, sq=0.f;
  const float* gq = gqk + (size_t)(l*8+b)*H_*D_;
  for (int jt=0; jt<32; jt++){
    int jb = jt*64;
    #pragma unroll
    for (int q=0;q<4;q++){
      int fid = t + q*256;
      int row = fid >> 4, jo = (fid & 15)*4;
      const float4 v = *(const float4*)(hs + (size_t)(s0+row)*D_ + jb + jo);
      float* lp = &lds[row*65 + jo];
      lp[0]=v.x; lp[1]=v.y; lp[2]=v.z; lp[3]=v.w;
    }
    __syncthreads();
    #pragma unroll
    for (int jj4=0; jj4<4; jj4++){
      int j = jq*16 + jj4*4;
      float x0 = lds[r*65+j], x1 = lds[r*65+j+1], x2 = lds[r*65+j+2], x3 = lds[r*65+j+3];
      sum += x0+x1+x2+x3;
      sq += x0*x0; sq += x1*x1; sq += x2*x2; sq += x3*x3;
      int jg = jb + j;
      #pragma unroll
      for(int h=0;h<16;h++){
        const float4 gv = *(const float4*)(gq + (size_t)h*D_ + jg);
        acc[h] += x0*gv.x + x1*gv.y + x2*gv.z + x3*gv.w;
      }
    }
    __syncthreads();
  }
  if (jq > 0){
    float* p = &lds[((jq-1)*64 + r)*18];
    #pragma unroll
    for(int h=0;h<16;h++) p[h]=acc[h];
    p[16]=sum; p[17]=sq;
  }
  __syncthreads();
  if (jq == 0){
    #pragma unroll
    for(int g3=0; g3<3; g3++){
      const float* p = &lds[(g3*64 + r)*18];
      #pragma unroll
      for(int h=0;h<16;h++) acc[h]+=p[h];
      sum += p[16]; sq += p[17];
    }
    float m = sum * (1.0f/D_);
    float var = sq * (1.0f/D_) - m*m;
    float rst = rsqrtf(var + EPS_);
    int s = s0 + r;
    int lb = l*8+b;
    mu[(size_t)lb*S_ + s] = m;
    rs[(size_t)lb*S_ + s] = rst;
    #pragma unroll
    for(int h=0;h<16;h++){
      float sgv = Sg[lb*H_ + h], sbv = Sb[lb*H_ + h];
      scores[((size_t)lb*H_ + h)*S_ + s] = rst*(acc[h] - m*sgv) + sbv;
    }
  }
}

// ---------------- kE1: softmax stats per (l,b,h): M, Sden, c ----------------
__global__ __launch_bounds__(256) void kE1(
    const float* __restrict__ scores, const float* __restrict__ mu, const float* __restrict__ rs,
    float* __restrict__ M, float* __restrict__ Sden, float* __restrict__ cc){
  int t=threadIdx.x; int h=blockIdx.x, b=blockIdx.y, l=blockIdx.z;
  int lb = l*8+b;
  const float* sc = scores + ((size_t)lb*H_ + h)*S_;
  __shared__ float red[256];
  __shared__ float red2[256];
  float mx = -1e30f;
  for (int s=t; s<S_; s+=256) mx = fmaxf(mx, sc[s]);
  red[t]=mx; __syncthreads();
  for(int off=128;off;off>>=1){ if(t<off) red[t]=fmaxf(red[t],red[t+off]); __syncthreads(); }
  float Mv = red[0];
  __syncthreads();
  float se=0.f, sce=0.f;
  const float* mup = mu + (size_t)lb*S_;
  const float* rsp = rs + (size_t)lb*S_;
  for (int s=t; s<S_; s+=256){
    float e = __expf(sc[s]-Mv);
    se += e;
    sce += e*rsp[s]*mup[s];
  }
  red[t]=se; red2[t]=sce; __syncthreads();
  for(int off=128;off;off>>=1){ if(t<off){red[t]+=red[t+off]; red2[t]+=red2[t+off];} __syncthreads(); }
  if(t==0){ M[lb*H_+h]=Mv; Sden[lb*H_+h]=red[0]; cc[lb*H_+h]=red2[0]/red[0]; }
}

// ---------------- kE2: u[l][b][s][h] = softmax * rstd ----------------
__global__ __launch_bounds__(256) void kE2(
    const float* __restrict__ scores, const float* __restrict__ rs,
    const float* __restrict__ M, const float* __restrict__ Sden,
    float* __restrict__ u){
  int t=threadIdx.x; int scb=blockIdx.x, b=blockIdx.y, l=blockIdx.z;
  int lb=l*8+b;
  int lin0 = t*8;
  int sl = lin0 >> 4;
  int h0 = lin0 & 15;
  int s = scb*128 + sl;
  float rstv = rs[(size_t)lb*S_ + s];
  float out[8];
  #pragma unroll
  for(int k=0;k<8;k++){
    int h = h0 + k;
    float e = __expf(scores[((size_t)lb*H_+h)*S_ + s] - M[lb*H_+h]);
    out[k] = e / Sden[lb*H_+h] * rstv;
  }
  float* up = u + ((size_t)lb*S_ + s)*H_ + h0;
  *(float4*)up     = make_float4(out[0],out[1],out[2],out[3]);
  *(float4*)(up+4) = make_float4(out[4],out[5],out[6],out[7]);
}

// ---------------- kF: A partials = sum_s u[h,s]*x[s,d] (reads hs 2nd time) ----------------
__global__ __launch_bounds__(256) void kF(
    const float* __restrict__ hs0, const float* __restrict__ hs1,
    const float* __restrict__ u, float* __restrict__ Fpart){
  int t=threadIdx.x;
  int sc = blockIdx.x>>1, dh = blockIdx.x&1;
  int b=blockIdx.y, l=blockIdx.z;
  int lb=l*8+b;
  const float* hs = (l==0?hs0:hs1) + (size_t)b*S_*D_;
  int d0 = dh*1024 + t*4;
  float acc[16][4];
  #pragma unroll
  for(int h=0;h<16;h++){
    #pragma unroll
    for(int k=0;k<4;k++) acc[h][k]=0.f;
  }
  int s0 = sc*128;
  for (int si=0; si<128; si++){
    int s = s0+si;
    const float* up = u + ((size_t)lb*S_ + s)*H_;
    float4 u0 = *(const float4*)up, u1 = *(const float4*)(up+4),
           u2 = *(const float4*)(up+8), u3 = *(const float4*)(up+12);
    float uu[16] = {u0.x,u0.y,u0.z,u0.w, u1.x,u1.y,u1.z,u1.w,
                    u2.x,u2.y,u2.z,u2.w, u3.x,u3.y,u3.z,u3.w};
    float4 x = *(const float4*)(hs + (size_t)s*D_ + d0);
    float xx[4]={x.x,x.y,x.z,x.w};
    #pragma unroll
    for(int h=0;h<16;h++){
      #pragma unroll
      for(int k=0;k<4;k++) acc[h][k] += uu[h]*xx[k];
    }
  }
  #pragma unroll
  for(int h=0;h<16;h++){
    float4 v = make_float4(acc[h][0],acc[h][1],acc[h][2],acc[h][3]);
    *(float4*)(Fpart + (((size_t)lb*16 + sc)*H_ + h)*D_ + d0) = v;
  }
}

// ---------------- kF2: combine partials, mult by gamma -> gAT[l][h][d][b] ----------------
__global__ __launch_bounds__(256) void kF2(
    const float* __restrict__ Fpart, const float* __restrict__ g, float* __restrict__ gAT){
  int n = blockIdx.x*256 + threadIdx.x;   // over l*16*2048 = 65536
  int d = n & (D_-1);
  int h = (n >> 11) & 15;
  int l = n >> 15;
  float gg = g[l*D_+d];
  float out[8];
  #pragma unroll
  for(int b=0;b<8;b++){
    float s=0.f;
    for(int scn=0;scn<16;scn++)
      s += Fpart[(((size_t)(l*8+b)*16 + scn)*H_ + h)*D_ + d];
    out[b]=gg*s;
  }
  float* op = gAT + (size_t)n*8;
  *(float4*)op     = make_float4(out[0],out[1],out[2],out[3]);
  *(float4*)(op+4) = make_float4(out[4],out[5],out[6],out[7]);
}

// ---------------- kG: o partials = gA @ Wv (+ Gv, Bv rows) ----------------
__global__ __launch_bounds__(256) void kG(
    const float* __restrict__ Wv, const float* __restrict__ gAT,
    const float* __restrict__ g, const float* __restrict__ bt,
    float* __restrict__ Opart){
  int t=threadIdx.x;
  int d4=blockIdx.x, h=blockIdx.y, l=blockIdx.z;
  int j = t & 127;
  int dg = rfl(t >> 7);
  const float* wv = Wv + (size_t)l*D_*D_ + h*HD_ + j;
  const float* gA = gAT + ((size_t)l*H_ + h)*D_*8;
  float acc[8]={0,0,0,0,0,0,0,0}; float ag=0.f, ab=0.f;
  int dstart = d4*512 + dg*256;
  #pragma unroll 2
  for (int dd=0; dd<256; dd++){
    int d = dstart+dd;
    float wvv = wv[(size_t)d*D_];
    const float* xa = gA + (size_t)d*8;
    #pragma unroll
    for(int r=0;r<8;r++) acc[r] += xa[r]*wvv;
    ag += g[l*D_+d]*wvv;
    ab += bt[l*D_+d]*wvv;
  }
  __shared__ float red[2][128][10];
  float* p = red[dg][j];
  #pragma unroll
  for(int r=0;r<8;r++) p[r]=acc[r];
  p[8]=ag; p[9]=ab;
  __syncthreads();
  if (t<128){
    const float* q0=red[0][t]; const float* q1=red[1][t];
    #pragma unroll
    for(int r=0;r<10;r++)
      atomicAdd(&Opart[(((size_t)l*H_+h)*HD_ + t)*10 + r], q0[r]+q1[r]);
  }
}

// ---------------- kG2: finalize o -> oT[l][d][b] ----------------
__global__ __launch_bounds__(256) void kG2(const float* __restrict__ Opart, const float* __restrict__ cc,
                    float* __restrict__ oT){
  int n = blockIdx.x*256 + threadIdx.x;  // over 2*16*128 = 4096
  int j = n & 127; int h = (n>>7) & 15; int l = n>>11;
  const float* p = Opart + (size_t)n*10;
  float ag=p[8], ab=p[9];
  #pragma unroll
  for(int b=0;b<8;b++){
    float c = cc[(l*8+b)*H_+h];
    oT[((size_t)l*D_ + h*HD_ + j)*8 + b] = p[b] - c*ag + ab;
  }
}

// ---------------- kInitH: hcatT = bo broadcast ----------------
__global__ void kInitH(const float* __restrict__ bo, float* __restrict__ hcatT){
  int n = blockIdx.x*256 + threadIdx.x;  // 32768
  hcatT[n] = bo[n>>3];
}

// ---------------- kH2: t1 = gelu(t1 + b1) ----------------
__global__ void kH2(float* __restrict__ t1T, const float* __restrict__ b1){
  int i = blockIdx.x*256 + threadIdx.x;  // 16384
  float bv = b1[i];
  float* p = t1T + (size_t)i*8;
  #pragma unroll
  for(int k=0;k<8;k++){
    float x = p[k] + bv;
    p[k] = 0.5f*x*(1.0f + erff(x*0.70710678118654752440f));
  }
}

// ---------------- kH2b: h2 = hcat + b2 ----------------
__global__ void kH2b(const float* __restrict__ hcatT, const float* __restrict__ b2, float* __restrict__ h2T){
  int j = blockIdx.x*256 + threadIdx.x;  // 4096
  float bv = b2[j];
  #pragma unroll
  for(int k=0;k<8;k++) h2T[(size_t)j*8+k] = hcatT[(size_t)j*8+k] + bv;
}

// ---------------- kH4: logits = h2 @ Wl + bl ----------------
__global__ __launch_bounds__(256) void kH4(const float* __restrict__ h2T, const float* __restrict__ Wl,
                    const float* __restrict__ bl, float* __restrict__ out){
  int t=threadIdx.x;
  float acc[8][2];
  #pragma unroll
  for(int b=0;b<8;b++){acc[b][0]=0.f;acc[b][1]=0.f;}
  for (int j=t; j<DC_; j+=256){
    float w0=Wl[j*2], w1=Wl[j*2+1];
    const float* hp = h2T + (size_t)j*8;
    #pragma unroll
    for(int b=0;b<8;b++){ float x=hp[b]; acc[b][0]+=x*w0; acc[b][1]+=x*w1; }
  }
  __shared__ float red[256][16];
  #pragma unroll
  for(int b=0;b<8;b++){ red[t][b*2]=acc[b][0]; red[t][b*2+1]=acc[b][1]; }
  __syncthreads();
  for(int off=128;off;off>>=1){ if(t<off){ for(int k=0;k<16;k++) red[t][k]+=red[t+off][k]; } __syncthreads(); }
  if (t<16) out[t] = red[0][t] + bl[t&1];
}

extern "C" void kernel_launch(void* const* d_in, const int* in_sizes, int n_in,
                              void* d_out, int out_size, void* d_ws, size_t ws_size,
                              hipStream_t stream) {
  (void)in_sizes; (void)n_in; (void)out_size;
  const float* hs0 = (const float*)d_in[0];
  const float* hs1 = (const float*)d_in[1];
  const int*   ids = (const int*)d_in[2];
  const float* ln_g = (const float*)d_in[3];
  const float* ln_b = (const float*)d_in[4];
  const float* Wq = (const float*)d_in[5];
  const float* Wk = (const float*)d_in[6];
  const float* Wv = (const float*)d_in[7];
  const float* Wo = (const float*)d_in[8];
  const float* bo = (const float*)d_in[9];
  const float* W1 = (const float*)d_in[10];
  const float* b1 = (const float*)d_in[11];
  const float* W2 = (const float*)d_in[12];
  const float* b2 = (const float*)d_in[13];
  const float* Wl = (const float*)d_in[14];
  const float* bl = (const float*)d_in[15];
  float* out = (float*)d_out;
  float* ws = (float*)d_ws;

  size_t o = 0;
  int* idx = (int*)ws;        o += 16;
  // ---- atomic-accumulated region (zero-init) ----
  float* qT = ws + o;         o += (size_t)L_*D_*8;        // 32768
  float* Sg = ws + o;         o += 256;
  float* Sb = ws + o;         o += 256;
  float* Opart = ws + o;      o += (size_t)L_*H_*HD_*10;   // 40960
  float* t1T = ws + o;        o += (size_t)I_*8;           // 131072
  size_t atomicFloats = o - 16;
  // ---- fully-written buffers ----
  float* lnlT = ws + o;       o += (size_t)L_*D_*8;
  float* gqk = ws + o;        o += (size_t)L_*8*H_*D_;
  float* mu = ws + o;         o += (size_t)L_*8*S_;
  float* rs_ = ws + o;        o += (size_t)L_*8*S_;
  float* scores = ws + o;     o += (size_t)L_*8*H_*S_;
  float* M = ws + o;          o += 256;
  float* Sden = ws + o;       o += 256;
  float* cc = ws + o;         o += 256;
  float* u = ws + o;          o += (size_t)L_*8*S_*H_;
  float* Fpart = ws + o;      o += (size_t)L_*8*16*H_*D_;  // 8388608
  float* gAT = ws + o;        o += (size_t)L_*H_*D_*8;
  float* oT = ws + o;         o += (size_t)L_*D_*8;
  float* hcatT = ws + o;      o += (size_t)DC_*8;
  float* h2T = ws + o;        o += (size_t)DC_*8;
  if (o*4 > ws_size) return;  // workspace too small (should not happen)

  hipMemsetAsync((void*)(ws + 16), 0, atomicFloats*4, stream);

  kA<<<8,256,0,stream>>>(ids, idx);
  kA2<<<dim3(8,2),256,0,stream>>>(hs0,hs1,idx,ln_g,ln_b,lnlT);
  // q[l,b,:] = lastln @ Wq
  gemv8<<<dim3(32,2,2),256,0,stream>>>(Wq, lnlT, qT, D_, D_, 2,
                                       (long)D_*D_, (long)D_*8, (long)D_*8);
  kC<<<dim3(4,16,2),256,0,stream>>>(Wk, qT, ln_g, ln_b, gqk, Sg, Sb);
  kD<<<dim3(32,8,2),256,0,stream>>>(hs0,hs1,gqk,Sg,Sb,scores,mu,rs_);
  kE1<<<dim3(16,8,2),256,0,stream>>>(scores,mu,rs_,M,Sden,cc);
  kE2<<<dim3(16,8,2),256,0,stream>>>(scores,rs_,M,Sden,u);
  kF<<<dim3(32,8,2),256,0,stream>>>(hs0,hs1,u,Fpart);
  kF2<<<256,256,0,stream>>>(Fpart, ln_g, gAT);
  kG<<<dim3(4,16,2),256,0,stream>>>(Wv, gAT, ln_g, ln_b, Opart);
  kG2<<<16,256,0,stream>>>(Opart, cc, oT);
  kInitH<<<128,256,0,stream>>>(bo, hcatT);
  // attn_out = o @ Wo (+bo via init), concat into hcatT
  gemv8<<<dim3(32,2,2),256,0,stream>>>(Wo, oT, hcatT, D_, D_, 2,
                                       (long)D_*D_, (long)D_*8, (long)D_*8);
  // t1 = hcat @ W1
  gemv8<<<dim3(256,2,1),256,0,stream>>>(W1, hcatT, t1T, DC_, I_, 2, 0,0,0);
  kH2<<<64,256,0,stream>>>(t1T, b1);
  kH2b<<<16,256,0,stream>>>(hcatT, b2, h2T);
  // h2 += t1 @ W2
  gemv8<<<dim3(64,8,1),256,0,stream>>>(W2, t1T, h2T, I_, DC_, 8, 0,0,0);
  kH4<<<1,256,0,stream>>>(h2T, Wl, bl, out);
}